// Round 1
// baseline (4361.060 us; speedup 1.0000x reference)
//
#include <hip/hip_runtime.h>

#define TB      256   // threads per block = 4*H gate rows
#define NBATCH  4     // batch elements per block
#define TSTEPS  512
#define DIN     32
#define HH      64

__device__ __forceinline__ float sigm(float x) {
    // 1/(1+e^-x); v_exp + v_rcp, 1-ulp class accuracy
    return __builtin_amdgcn_rcpf(1.0f + __expf(-x));
}
__device__ __forceinline__ float tanh_fast(float x) {
    // tanh(x) = 1 - 2/(e^{2x}+1)
    return 1.0f - 2.0f * __builtin_amdgcn_rcpf(1.0f + __expf(2.0f * x));
}

__global__ void __launch_bounds__(TB, 1)
lstm2_fused_kernel(const float* __restrict__ x,
                   const float* __restrict__ Wih0, const float* __restrict__ Whh0,
                   const float* __restrict__ bih0, const float* __restrict__ bhh0,
                   const float* __restrict__ Wih1, const float* __restrict__ Whh1,
                   const float* __restrict__ bih1, const float* __restrict__ bhh1,
                   const float* __restrict__ W1,   const float* __restrict__ b1,
                   const float* __restrict__ W2,   const float* __restrict__ b2,
                   float* __restrict__ out)
{
    const int tid = threadIdx.x;            // gate row g in [0,256)
    const int b0  = blockIdx.x * NBATCH;    // first batch elem of this block

    // ---- per-thread weight rows in registers (224 VGPRs) ----
    float wih0[DIN], whh0[HH], wih1[HH], whh1[HH];
    {
        const float4* p = (const float4*)(Wih0 + tid * DIN);
        #pragma unroll
        for (int k = 0; k < DIN/4; ++k) {
            float4 v = p[k];
            wih0[4*k]=v.x; wih0[4*k+1]=v.y; wih0[4*k+2]=v.z; wih0[4*k+3]=v.w;
        }
    }
    {
        const float4* p = (const float4*)(Whh0 + tid * HH);
        #pragma unroll
        for (int k = 0; k < HH/4; ++k) {
            float4 v = p[k];
            whh0[4*k]=v.x; whh0[4*k+1]=v.y; whh0[4*k+2]=v.z; whh0[4*k+3]=v.w;
        }
    }
    {
        const float4* p = (const float4*)(Wih1 + tid * HH);
        #pragma unroll
        for (int k = 0; k < HH/4; ++k) {
            float4 v = p[k];
            wih1[4*k]=v.x; wih1[4*k+1]=v.y; wih1[4*k+2]=v.z; wih1[4*k+3]=v.w;
        }
    }
    {
        const float4* p = (const float4*)(Whh1 + tid * HH);
        #pragma unroll
        for (int k = 0; k < HH/4; ++k) {
            float4 v = p[k];
            whh1[4*k]=v.x; whh1[4*k+1]=v.y; whh1[4*k+2]=v.z; whh1[4*k+3]=v.w;
        }
    }
    const float bias0 = bih0[tid] + bhh0[tid];
    const float bias1 = bih1[tid] + bhh1[tid];

    // ---- LDS: double-buffered x, h states, gate pre-activations ----
    __shared__ __align__(16) float xs [2][NBATCH][DIN];
    __shared__ __align__(16) float h0s[NBATCH][HH];
    __shared__ __align__(16) float h1s[NBATCH][HH];
    __shared__ __align__(16) float z0s[NBATCH][TB];
    __shared__ __align__(16) float z1s[NBATCH][TB];
    __shared__ __align__(16) float hid[NBATCH][32];

    const int ub = tid >> 6, uj = tid & 63;   // (batch, hidden-unit) update pair
    h0s[ub][uj] = 0.0f;
    h1s[ub][uj] = 0.0f;
    float c0 = 0.0f, c1 = 0.0f;

    const int  xb  = tid >> 5, xk = tid & 31; // x-loader role (tid < 128)
    const bool isx = (tid < NBATCH * DIN);
    if (isx) xs[0][xb][xk] = x[(size_t)(b0 + xb) * TSTEPS * DIN + xk];
    __syncthreads();

    for (int step = 0; step < TSTEPS; ++step) {
        const int cur = step & 1;

        // prefetch next timestep's x (latency hidden behind this step's compute)
        float xnext = 0.0f;
        if (isx && step + 1 < TSTEPS)
            xnext = x[((size_t)(b0 + xb) * TSTEPS + (step + 1)) * DIN + xk];

        // ---- phase 1: layer-0 gate pre-activations for all NBATCH elems ----
        float acc0[NBATCH];
        #pragma unroll
        for (int b = 0; b < NBATCH; ++b) {
            float a = bias0;
            const float4* xv = (const float4*)xs[cur][b];
            #pragma unroll
            for (int k = 0; k < DIN/4; ++k) {
                float4 v = xv[k];
                a = fmaf(wih0[4*k  ], v.x, a);
                a = fmaf(wih0[4*k+1], v.y, a);
                a = fmaf(wih0[4*k+2], v.z, a);
                a = fmaf(wih0[4*k+3], v.w, a);
            }
            const float4* hv = (const float4*)h0s[b];
            #pragma unroll
            for (int k = 0; k < HH/4; ++k) {
                float4 v = hv[k];
                a = fmaf(whh0[4*k  ], v.x, a);
                a = fmaf(whh0[4*k+1], v.y, a);
                a = fmaf(whh0[4*k+2], v.z, a);
                a = fmaf(whh0[4*k+3], v.w, a);
            }
            acc0[b] = a;
        }
        #pragma unroll
        for (int b = 0; b < NBATCH; ++b) z0s[b][tid] = acc0[b];
        __syncthreads();

        // ---- phase 2: layer-0 cell/hidden update (one (b,j) pair per thread) ----
        {
            float zi = z0s[ub][uj], zf = z0s[ub][64 + uj];
            float zg = z0s[ub][128 + uj], zo = z0s[ub][192 + uj];
            float ig = sigm(zi), fg = sigm(zf), gg = tanh_fast(zg), og = sigm(zo);
            c0 = fg * c0 + ig * gg;
            h0s[ub][uj] = og * tanh_fast(c0);
        }
        __syncthreads();

        // ---- phase 3: layer-1 gate pre-activations ----
        float acc1[NBATCH];
        #pragma unroll
        for (int b = 0; b < NBATCH; ++b) {
            float a = bias1;
            const float4* gv = (const float4*)h0s[b];
            #pragma unroll
            for (int k = 0; k < HH/4; ++k) {
                float4 v = gv[k];
                a = fmaf(wih1[4*k  ], v.x, a);
                a = fmaf(wih1[4*k+1], v.y, a);
                a = fmaf(wih1[4*k+2], v.z, a);
                a = fmaf(wih1[4*k+3], v.w, a);
            }
            const float4* hv = (const float4*)h1s[b];
            #pragma unroll
            for (int k = 0; k < HH/4; ++k) {
                float4 v = hv[k];
                a = fmaf(whh1[4*k  ], v.x, a);
                a = fmaf(whh1[4*k+1], v.y, a);
                a = fmaf(whh1[4*k+2], v.z, a);
                a = fmaf(whh1[4*k+3], v.w, a);
            }
            acc1[b] = a;
        }
        #pragma unroll
        for (int b = 0; b < NBATCH; ++b) z1s[b][tid] = acc1[b];
        __syncthreads();

        // ---- phase 4: layer-1 cell/hidden update + stash prefetched x ----
        {
            float zi = z1s[ub][uj], zf = z1s[ub][64 + uj];
            float zg = z1s[ub][128 + uj], zo = z1s[ub][192 + uj];
            float ig = sigm(zi), fg = sigm(zf), gg = tanh_fast(zg), og = sigm(zo);
            c1 = fg * c1 + ig * gg;
            h1s[ub][uj] = og * tanh_fast(c1);
        }
        if (isx && step + 1 < TSTEPS) xs[cur ^ 1][xb][xk] = xnext;
        __syncthreads();
    }

    // ---- head: hidden = relu(h_last @ W1^T + b1); out = hidden @ W2^T + b2 ----
    if (tid < NBATCH * 32) {
        int b = tid >> 5, m = tid & 31;
        float a = b1[m];
        const float* w = W1 + m * HH;
        #pragma unroll
        for (int j = 0; j < HH; ++j) a = fmaf(w[j], h1s[b][j], a);
        hid[b][m] = fmaxf(a, 0.0f);
    }
    __syncthreads();
    if (tid < NBATCH) {
        float a = b2[0];
        #pragma unroll
        for (int m = 0; m < 32; ++m) a = fmaf(W2[m], hid[tid][m], a);
        out[b0 + tid] = a;
    }
}

extern "C" void kernel_launch(void* const* d_in, const int* in_sizes, int n_in,
                              void* d_out, int out_size, void* d_ws, size_t ws_size,
                              hipStream_t stream) {
    const float* x    = (const float*)d_in[0];
    const float* Wih0 = (const float*)d_in[1];
    const float* Whh0 = (const float*)d_in[2];
    const float* bih0 = (const float*)d_in[3];
    const float* bhh0 = (const float*)d_in[4];
    const float* Wih1 = (const float*)d_in[5];
    const float* Whh1 = (const float*)d_in[6];
    const float* bih1 = (const float*)d_in[7];
    const float* bhh1 = (const float*)d_in[8];
    const float* W1   = (const float*)d_in[9];
    const float* b1   = (const float*)d_in[10];
    const float* W2   = (const float*)d_in[11];
    const float* b2   = (const float*)d_in[12];
    float* out = (float*)d_out;

    hipLaunchKernelGGL(lstm2_fused_kernel, dim3(1024 / NBATCH), dim3(TB), 0, stream,
                       x, Wih0, Whh0, bih0, bhh0, Wih1, Whh1, bih1, bhh1,
                       W1, b1, W2, b2, out);
}

// Round 2
// 841.115 us; speedup vs baseline: 5.1849x; 5.1849x over previous
//
#include <hip/hip_runtime.h>

#define T       512
#define DIN     32
#define HCELLS  64
#define NB      16      // batch elems per block (MFMA N dim)
#define TB      256     // 4 waves
#define GRID    64      // 1024 / NB

typedef _Float16 half8  __attribute__((ext_vector_type(8)));
typedef _Float16 half4v __attribute__((ext_vector_type(4)));
typedef _Float16 half2v __attribute__((ext_vector_type(2)));
typedef float    float4v __attribute__((ext_vector_type(4)));

// LDS B-operand buffers (fp16), stride 40 halves per n-row (80 B -> <=2-way banks)
#define STRIDE  40
#define B0H_OFF 0                   // [2][3][16][40]  x | h0 (layer-0 B)
#define B0L_OFF (2*3*16*STRIDE)
#define B1H_OFF (B0L_OFF + 2*3*16*STRIDE)   // [2][4][16][40]  h0 | h1 (layer-1 B)
#define B1L_OFF (B1H_OFF + 2*4*16*STRIDE)
#define SB_HALFS (B1L_OFF + 2*4*16*STRIDE)  // total halves

__device__ __forceinline__ int idx0(int p, int kt, int n, int k) {
    return ((p * 3 + kt) * 16 + n) * STRIDE + k;
}
__device__ __forceinline__ int idx1(int p, int kt, int n, int k) {
    return ((p * 4 + kt) * 16 + n) * STRIDE + k;
}

__device__ __forceinline__ float sigm(float x) {
    return __builtin_amdgcn_rcpf(1.0f + __expf(-x));
}
__device__ __forceinline__ float tanh_fast(float x) {
    return 1.0f - 2.0f * __builtin_amdgcn_rcpf(1.0f + __expf(2.0f * x));
}

// split fp32 -> (hi, lo) fp16 pair
__device__ __forceinline__ void split8(const float* v, half8& hi, half8& lo) {
    #pragma unroll
    for (int e = 0; e < 8; ++e) {
        _Float16 h = (_Float16)v[e];
        hi[e] = h;
        lo[e] = (_Float16)(v[e] - (float)h);
    }
}

__global__ void __launch_bounds__(TB, 1)
lstm2_mfma_kernel(const float* __restrict__ x,
                  const float* __restrict__ Wih0, const float* __restrict__ Whh0,
                  const float* __restrict__ bih0, const float* __restrict__ bhh0,
                  const float* __restrict__ Wih1, const float* __restrict__ Whh1,
                  const float* __restrict__ bih1, const float* __restrict__ bhh1,
                  const float* __restrict__ W1,   const float* __restrict__ b1,
                  const float* __restrict__ W2,   const float* __restrict__ b2,
                  float* __restrict__ out)
{
    const int tid  = threadIdx.x;
    const int w    = tid >> 6;          // wave 0..3
    const int lane = tid & 63;
    const int n16  = lane & 15;         // MFMA free-index / local batch
    const int q    = lane >> 4;         // quad 0..3
    const int j0   = w * 16 + q * 4;    // this thread's hidden-unit base (4 rows)
    const int b0   = blockIdx.x * NB;   // global batch base

    __shared__ __align__(16) _Float16 SB[SB_HALFS];
    __shared__ __align__(16) float HS[16 * 68 + 16 * 33];  // head scratch

    // ---------------- A-fragments (weights, hi/lo fp16) in registers ----------------
    // wave w owns row-tiles rt = l*4 + w  (rows l*64 + w*16 .. +15) => gate l, j-range j0..j0+3
    half8 a0h[4][3], a0l[4][3];   // layer0: K = 96 (x 32 | h0 64)
    half8 a1h[4][4], a1l[4][4];   // layer1: K = 128 (h0 64 | h1 64)
    float4v bias0v[4], bias1v[4];

    #pragma unroll
    for (int l = 0; l < 4; ++l) {
        const int row = (l * 4 + w) * 16 + n16;
        float v[8];
        // layer0 kt=0 : Wih0 cols q*8..q*8+7
        {
            const float4* p = (const float4*)(Wih0 + row * DIN + q * 8);
            float4 u0 = p[0], u1 = p[1];
            v[0]=u0.x; v[1]=u0.y; v[2]=u0.z; v[3]=u0.w;
            v[4]=u1.x; v[5]=u1.y; v[6]=u1.z; v[7]=u1.w;
            split8(v, a0h[l][0], a0l[l][0]);
        }
        // layer0 kt=1,2 : Whh0 cols (kt-1)*32 + q*8
        #pragma unroll
        for (int kt = 1; kt < 3; ++kt) {
            const float4* p = (const float4*)(Whh0 + row * HCELLS + (kt - 1) * 32 + q * 8);
            float4 u0 = p[0], u1 = p[1];
            v[0]=u0.x; v[1]=u0.y; v[2]=u0.z; v[3]=u0.w;
            v[4]=u1.x; v[5]=u1.y; v[6]=u1.z; v[7]=u1.w;
            split8(v, a0h[l][kt], a0l[l][kt]);
        }
        // layer1 kt=0,1 : Wih1 ; kt=2,3 : Whh1
        #pragma unroll
        for (int kt = 0; kt < 4; ++kt) {
            const float* base = (kt < 2) ? (Wih1 + row * HCELLS + kt * 32)
                                         : (Whh1 + row * HCELLS + (kt - 2) * 32);
            const float4* p = (const float4*)(base + q * 8);
            float4 u0 = p[0], u1 = p[1];
            v[0]=u0.x; v[1]=u0.y; v[2]=u0.z; v[3]=u0.w;
            v[4]=u1.x; v[5]=u1.y; v[6]=u1.z; v[7]=u1.w;
            split8(v, a1h[l][kt], a1l[l][kt]);
        }
        // biases for rows l*64 + j0 .. +3 (init the accumulator -> no epilogue add)
        const int r0 = l * 64 + j0;
        float4v bi = *(const float4v*)(bih0 + r0);
        float4v bh = *(const float4v*)(bhh0 + r0);
        bias0v[l] = bi + bh;
        bi = *(const float4v*)(bih1 + r0);
        bh = *(const float4v*)(bhh1 + r0);
        bias1v[l] = bi + bh;
    }

    // ---------------- zero LDS, stage x(t=0) ----------------
    for (int i = tid; i < SB_HALFS / 2; i += TB) ((int*)SB)[i] = 0;
    __syncthreads();

    const int nx = tid >> 4;            // x-loader: batch 0..15
    const int kp = (tid & 15) * 2;      // x-loader: k pair 0..30
    {
        float2 xv = *(const float2*)(x + ((size_t)(b0 + nx) * T + 0) * DIN + kp);
        _Float16 h0x = (_Float16)xv.x, h1x = (_Float16)xv.y;
        half2v hi = {h0x, h1x};
        half2v lo = {(_Float16)(xv.x - (float)h0x), (_Float16)(xv.y - (float)h1x)};
        *(half2v*)&SB[B0H_OFF + idx0(0, 0, nx, kp)] = hi;
        *(half2v*)&SB[B0L_OFF + idx0(0, 0, nx, kp)] = lo;
    }
    __syncthreads();

    float c0r[4] = {0, 0, 0, 0}, c1r[4] = {0, 0, 0, 0};
    float hlast[4];

    const int ktw0 = 1 + (j0 >> 5);     // where this thread's h0 goes in B0 (k = 32 + j)
    const int ktw1 = (j0 >> 5);         // where h0 goes in B1 (k = j)
    const int kk   = j0 & 31;

    // ---------------- time loop: all writes -> parity nxt, cross-step reads -> cur ----
    #pragma unroll 2
    for (int t = 0; t < T; ++t) {
        const int cur = t & 1, nxt = cur ^ 1;

        // prefetch next x early (L2/L3-warm, consumed at end of step)
        float2 xv;
        const bool havex = (t + 1 < T);
        if (havex) xv = *(const float2*)(x + ((size_t)(b0 + nx) * T + (t + 1)) * DIN + kp);

        // ---- layer 0: z = [Wih0|Whh0] . [x;h0] + b ----
        float4v acc[4];
        #pragma unroll
        for (int l = 0; l < 4; ++l) acc[l] = bias0v[l];
        #pragma unroll
        for (int kt = 0; kt < 3; ++kt) {
            half8 bh = *(const half8*)&SB[B0H_OFF + idx0(cur, kt, n16, q * 8)];
            half8 bl = *(const half8*)&SB[B0L_OFF + idx0(cur, kt, n16, q * 8)];
            #pragma unroll
            for (int l = 0; l < 4; ++l) {
                acc[l] = __builtin_amdgcn_mfma_f32_16x16x32_f16(a0h[l][kt], bh, acc[l], 0, 0, 0);
                acc[l] = __builtin_amdgcn_mfma_f32_16x16x32_f16(a0l[l][kt], bh, acc[l], 0, 0, 0);
                acc[l] = __builtin_amdgcn_mfma_f32_16x16x32_f16(a0h[l][kt], bl, acc[l], 0, 0, 0);
            }
        }
        // in-thread cell update: gates i,f,g,o = acc[0..3], rows j0..j0+3, batch n16
        {
            half4v hh, hl;
            #pragma unroll
            for (int r = 0; r < 4; ++r) {
                float ig = sigm(acc[0][r]);
                float fg = sigm(acc[1][r]);
                float gg = tanh_fast(acc[2][r]);
                float og = sigm(acc[3][r]);
                c0r[r] = fg * c0r[r] + ig * gg;
                float h = og * tanh_fast(c0r[r]);
                _Float16 hh16 = (_Float16)h;
                hh[r] = hh16;
                hl[r] = (_Float16)(h - (float)hh16);
            }
            *(half4v*)&SB[B0H_OFF + idx0(nxt, ktw0, n16, kk)] = hh;
            *(half4v*)&SB[B0L_OFF + idx0(nxt, ktw0, n16, kk)] = hl;
            *(half4v*)&SB[B1H_OFF + idx1(nxt, ktw1, n16, kk)] = hh;
            *(half4v*)&SB[B1L_OFF + idx1(nxt, ktw1, n16, kk)] = hl;
        }
        __syncthreads();   // h0(t) visible

        // ---- layer 1: z = [Wih1|Whh1] . [h0(t); h1(t-1)] + b ----
        #pragma unroll
        for (int l = 0; l < 4; ++l) acc[l] = bias1v[l];
        #pragma unroll
        for (int kt = 0; kt < 4; ++kt) {
            const int p = (kt < 2) ? nxt : cur;   // h0(t) fresh | h1(t-1) old
            half8 bh = *(const half8*)&SB[B1H_OFF + idx1(p, kt, n16, q * 8)];
            half8 bl = *(const half8*)&SB[B1L_OFF + idx1(p, kt, n16, q * 8)];
            #pragma unroll
            for (int l = 0; l < 4; ++l) {
                acc[l] = __builtin_amdgcn_mfma_f32_16x16x32_f16(a1h[l][kt], bh, acc[l], 0, 0, 0);
                acc[l] = __builtin_amdgcn_mfma_f32_16x16x32_f16(a1l[l][kt], bh, acc[l], 0, 0, 0);
                acc[l] = __builtin_amdgcn_mfma_f32_16x16x32_f16(a1h[l][kt], bl, acc[l], 0, 0, 0);
            }
        }
        {
            half4v hh, hl;
            #pragma unroll
            for (int r = 0; r < 4; ++r) {
                float ig = sigm(acc[0][r]);
                float fg = sigm(acc[1][r]);
                float gg = tanh_fast(acc[2][r]);
                float og = sigm(acc[3][r]);
                c1r[r] = fg * c1r[r] + ig * gg;
                float h = og * tanh_fast(c1r[r]);
                hlast[r] = h;
                _Float16 hh16 = (_Float16)h;
                hh[r] = hh16;
                hl[r] = (_Float16)(h - (float)hh16);
            }
            *(half4v*)&SB[B1H_OFF + idx1(nxt, 2 + ktw1, n16, kk)] = hh;
            *(half4v*)&SB[B1L_OFF + idx1(nxt, 2 + ktw1, n16, kk)] = hl;
        }
        // stage x(t+1)
        if (havex) {
            _Float16 h0x = (_Float16)xv.x, h1x = (_Float16)xv.y;
            half2v hi = {h0x, h1x};
            half2v lo = {(_Float16)(xv.x - (float)h0x), (_Float16)(xv.y - (float)h1x)};
            *(half2v*)&SB[B0H_OFF + idx0(nxt, 0, nx, kp)] = hi;
            *(half2v*)&SB[B0L_OFF + idx0(nxt, 0, nx, kp)] = lo;
        }
        __syncthreads();
    }

    // ---------------- head: relu(h1 @ W1^T + b1) @ W2^T + b2 ----------------
    float* h1f = HS;             // [16][68]
    float* hid = HS + 16 * 68;   // [16][33]
    *(float4*)&h1f[n16 * 68 + j0] = *(const float4*)hlast;
    __syncthreads();

    {
        const int n2 = tid >> 4, m = tid & 15;
        float s0 = b1[m], s1 = b1[m + 16];
        const float* w0p = W1 + m * HCELLS;
        const float* w1p = W1 + (m + 16) * HCELLS;
        #pragma unroll
        for (int j = 0; j < HCELLS; ++j) {
            float hv = h1f[n2 * 68 + j];
            s0 = fmaf(w0p[j], hv, s0);
            s1 = fmaf(w1p[j], hv, s1);
        }
        hid[n2 * 33 + m]      = fmaxf(s0, 0.0f);
        hid[n2 * 33 + m + 16] = fmaxf(s1, 0.0f);
    }
    __syncthreads();

    if (tid < NB) {
        float s = b2[0];
        #pragma unroll
        for (int m = 0; m < 32; ++m) s = fmaf(W2[m], hid[tid * 33 + m], s);
        out[b0 + tid] = s;
    }
}

extern "C" void kernel_launch(void* const* d_in, const int* in_sizes, int n_in,
                              void* d_out, int out_size, void* d_ws, size_t ws_size,
                              hipStream_t stream) {
    const float* x    = (const float*)d_in[0];
    const float* Wih0 = (const float*)d_in[1];
    const float* Whh0 = (const float*)d_in[2];
    const float* bih0 = (const float*)d_in[3];
    const float* bhh0 = (const float*)d_in[4];
    const float* Wih1 = (const float*)d_in[5];
    const float* Whh1 = (const float*)d_in[6];
    const float* bih1 = (const float*)d_in[7];
    const float* bhh1 = (const float*)d_in[8];
    const float* W1   = (const float*)d_in[9];
    const float* b1   = (const float*)d_in[10];
    const float* W2   = (const float*)d_in[11];
    const float* b2   = (const float*)d_in[12];
    float* out = (float*)d_out;

    hipLaunchKernelGGL(lstm2_mfma_kernel, dim3(GRID), dim3(TB), 0, stream,
                       x, Wih0, Whh0, bih0, bhh0, Wih1, Whh1, bih1, bhh1,
                       W1, b1, W2, b2, out);
}